// Round 1
// baseline (1236.661 us; speedup 1.0000x reference)
//
#include <hip/hip_runtime.h>
#include <hip/hip_bf16.h>
#include <math.h>

#define D_    256
#define NT_   8192
#define NN_   512
#define B_    16
#define H_    8
#define DH_   32
#define EPG_  16384
#define BN_EPS 1e-5f

__device__ __forceinline__ float gelu_exact(float x) {
    return 0.5f * x * (1.0f + erff(x * 0.70710678118654752f));
}

// ---------------- GEMM: C = A(MxK) @ B(NxK)^T (+bias) (+epilogue) ----------
// EPI: 0 = none, 1 = gelu, 2 = resid + batchnorm
template<int EPI>
__global__ __launch_bounds__(256)
void gemm_bt(const float* __restrict__ A, const float* __restrict__ Bw,
             const float* __restrict__ bias, float* __restrict__ C,
             int M, int N, int K,
             const float* __restrict__ resid,
             const float* __restrict__ bng, const float* __restrict__ bnb,
             const float* __restrict__ bnm, const float* __restrict__ bnv)
{
    __shared__ float As[16][128];
    __shared__ float Bs[16][64];
    const int bm = blockIdx.y * 128;
    const int bn = blockIdx.x * 64;
    const int tid = threadIdx.x;
    const int tx = tid & 15;          // 4 output cols
    const int ty = tid >> 4;          // 8 output rows
    const int alm = tid >> 1, alk = (tid & 1) << 3;
    const int blm = tid >> 2, blk_ = (tid & 3) << 2;
    float acc[8][4] = {};
    for (int k0 = 0; k0 < K; k0 += 16) {
        #pragma unroll
        for (int u = 0; u < 2; ++u) {
            float4 a4 = *(const float4*)(A + (size_t)(bm + alm) * K + k0 + alk + u * 4);
            As[alk + u * 4 + 0][alm] = a4.x;
            As[alk + u * 4 + 1][alm] = a4.y;
            As[alk + u * 4 + 2][alm] = a4.z;
            As[alk + u * 4 + 3][alm] = a4.w;
        }
        {
            float4 b4 = *(const float4*)(Bw + (size_t)(bn + blm) * K + k0 + blk_);
            Bs[blk_ + 0][blm] = b4.x; Bs[blk_ + 1][blm] = b4.y;
            Bs[blk_ + 2][blm] = b4.z; Bs[blk_ + 3][blm] = b4.w;
        }
        __syncthreads();
        #pragma unroll
        for (int k = 0; k < 16; ++k) {
            float a[8], b[4];
            *(float4*)&a[0] = *(const float4*)&As[k][ty * 8];
            *(float4*)&a[4] = *(const float4*)&As[k][ty * 8 + 4];
            *(float4*)&b[0] = *(const float4*)&Bs[k][tx * 4];
            #pragma unroll
            for (int i = 0; i < 8; ++i)
                #pragma unroll
                for (int j = 0; j < 4; ++j)
                    acc[i][j] += a[i] * b[j];
        }
        __syncthreads();
    }
    #pragma unroll
    for (int i = 0; i < 8; ++i) {
        const int m = bm + ty * 8 + i;
        float4 o;
        float* op = &o.x;
        #pragma unroll
        for (int j = 0; j < 4; ++j) {
            const int n = bn + tx * 4 + j;
            float v = acc[i][j];
            if (bias) v += bias[n];
            if (EPI == 1) v = gelu_exact(v);
            if (EPI == 2) {
                v += resid[(size_t)m * N + n];
                v = (v - bnm[n]) * (bng[n] * rsqrtf(bnv[n] + BN_EPS)) + bnb[n];
            }
            op[j] = v;
        }
        *(float4*)(C + (size_t)m * N + bn + tx * 4) = o;
    }
}

// ---------------- GCN SpMM via per-(graph, dim-chunk) LDS accumulation -----
__global__ __launch_bounds__(256)
void gcn_spmm(const int* __restrict__ rows, const int* __restrict__ cols,
              const float* __restrict__ vals, const float* __restrict__ hl,
              float* __restrict__ agg)
{
    const int b  = blockIdx.x >> 3;
    const int dc = (blockIdx.x & 7) << 5;   // dim chunk base (0..224)
    __shared__ float acc[NN_][DH_];          // 64 KiB
    float* accf = &acc[0][0];
    const int tid = threadIdx.x;
    for (int i = tid; i < NN_ * DH_ / 4; i += 256)
        *(float4*)&accf[i * 4] = make_float4(0.f, 0.f, 0.f, 0.f);
    __syncthreads();
    const int lane = tid & 63;
    const int half = lane >> 5;
    const int d    = tid & 31;
    const int wid  = tid >> 6;
    const int ebase = b * EPG_;
    for (int e0 = wid * 2; e0 < EPG_; e0 += 8) {
        const int e = ebase + e0 + half;
        const int r = rows[e] - b * NN_;
        const int c = cols[e];
        const float v = vals[e];
        const float hv = hl[(size_t)c * D_ + dc + d];
        atomicAdd(&acc[r][d], v * hv);
    }
    __syncthreads();
    for (int i = tid; i < NN_ * DH_ / 4; i += 256) {
        const int r  = (i * 4) >> 5;
        const int dd = (i * 4) & 31;
        *(float4*)(agg + ((size_t)(b * NN_ + r)) * D_ + dc + dd) = *(const float4*)&accf[i * 4];
    }
}

// ---------------- x1 = bn1(x + gelu(agg)) ----------------------------------
__global__ __launch_bounds__(256)
void fuse_gcn(const float* __restrict__ x, const float* __restrict__ agg,
              float* __restrict__ x1,
              const float* __restrict__ g, const float* __restrict__ bb,
              const float* __restrict__ m, const float* __restrict__ v)
{
    const int i = blockIdx.x * 256 + threadIdx.x;   // float4 index
    const int d0 = (i & 63) << 2;
    float4 a4 = *(const float4*)(agg + (size_t)i * 4);
    float4 x4 = *(const float4*)(x + (size_t)i * 4);
    float av[4] = {a4.x, a4.y, a4.z, a4.w};
    float xv[4] = {x4.x, x4.y, x4.z, x4.w};
    float4 o;
    float* op = &o.x;
    #pragma unroll
    for (int j = 0; j < 4; ++j) {
        const int dd = d0 + j;
        const float t = xv[j] + gelu_exact(av[j]);
        op[j] = (t - m[dd]) * (g[dd] * rsqrtf(v[dd] + BN_EPS)) + bb[dd];
    }
    *(float4*)(x1 + (size_t)i * 4) = o;
}

// ---------------- fused attention: per (b, h, 32-row q-tile) ----------------
__global__ __launch_bounds__(256)
void attn_fused(const float* __restrict__ qkv, float* __restrict__ ctx)
{
    const int qt = blockIdx.x & 15;
    const int bh = blockIdx.x >> 4;
    const int b = bh >> 3, h = bh & 7;
    __shared__ float Sb[32][520];    // score rows (padded)
    __shared__ float Qt_[32][33];    // d-major Q tile
    __shared__ float Kt_[32][64];    // d-major K tile
    __shared__ float Vs[64][36];     // row-major V tile (padded)
    __shared__ float red[32][8];
    __shared__ float rowsum[32];
    __shared__ float rowmax[32];
    const int tid = threadIdx.x;
    const float scale = 0.17677669529663687f;   // 1/sqrt(32)
    const float* base = qkv + (size_t)b * NN_ * 768;

    {   // load Q tile transposed
        const int row = tid >> 3, dq = (tid & 7) << 2;
        float4 q4 = *(const float4*)(base + (size_t)(qt * 32 + row) * 768 + h * 32 + dq);
        Qt_[dq + 0][row] = q4.x; Qt_[dq + 1][row] = q4.y;
        Qt_[dq + 2][row] = q4.z; Qt_[dq + 3][row] = q4.w;
    }
    __syncthreads();

    const int tx = tid & 15, ty = tid >> 4;
    for (int kt = 0; kt < 8; ++kt) {
        #pragma unroll
        for (int u = 0; u < 2; ++u) {
            const int f = tid + 256 * u;
            const int row = f >> 3, dq = (f & 7) << 2;
            float4 k4 = *(const float4*)(base + (size_t)(kt * 64 + row) * 768 + 256 + h * 32 + dq);
            Kt_[dq + 0][row] = k4.x; Kt_[dq + 1][row] = k4.y;
            Kt_[dq + 2][row] = k4.z; Kt_[dq + 3][row] = k4.w;
        }
        __syncthreads();
        float acc[2][4] = {};
        #pragma unroll
        for (int dd = 0; dd < 32; ++dd) {
            const float q0 = Qt_[dd][ty];
            const float q1 = Qt_[dd][ty + 16];
            float4 kv = *(const float4*)&Kt_[dd][tx << 2];
            float kk[4] = {kv.x, kv.y, kv.z, kv.w};
            #pragma unroll
            for (int j = 0; j < 4; ++j) {
                acc[0][j] += q0 * kk[j];
                acc[1][j] += q1 * kk[j];
            }
        }
        #pragma unroll
        for (int i = 0; i < 2; ++i) {
            float4 s4 = make_float4(acc[i][0] * scale, acc[i][1] * scale,
                                    acc[i][2] * scale, acc[i][3] * scale);
            *(float4*)&Sb[ty + 16 * i][kt * 64 + (tx << 2)] = s4;
        }
        __syncthreads();
    }

    {   // softmax: unnormalized exp, keep row sums
        const int row = tid >> 3, sub = tid & 7;
        float mx = -1e30f;
        for (int c = sub * 64; c < sub * 64 + 64; c += 4) {
            float4 s4 = *(const float4*)&Sb[row][c];
            mx = fmaxf(mx, fmaxf(fmaxf(s4.x, s4.y), fmaxf(s4.z, s4.w)));
        }
        red[row][sub] = mx;
        __syncthreads();
        if (sub == 0) {
            float m2 = red[row][0];
            #pragma unroll
            for (int t = 1; t < 8; ++t) m2 = fmaxf(m2, red[row][t]);
            rowmax[row] = m2;
        }
        __syncthreads();
        const float M = rowmax[row];
        float sum = 0.f;
        for (int c = sub * 64; c < sub * 64 + 64; c += 4) {
            float4 s4 = *(const float4*)&Sb[row][c];
            s4.x = __expf(s4.x - M); s4.y = __expf(s4.y - M);
            s4.z = __expf(s4.z - M); s4.w = __expf(s4.w - M);
            sum += s4.x + s4.y + s4.z + s4.w;
            *(float4*)&Sb[row][c] = s4;
        }
        red[row][sub] = sum;
        __syncthreads();
        if (sub == 0) {
            float s2 = 0.f;
            #pragma unroll
            for (int t = 0; t < 8; ++t) s2 += red[row][t];
            rowsum[row] = s2;
        }
        __syncthreads();
    }

    // PV
    const int ptx = tid & 7, pty = tid >> 3;
    float4 cacc = make_float4(0.f, 0.f, 0.f, 0.f);
    for (int kt = 0; kt < 8; ++kt) {
        #pragma unroll
        for (int u = 0; u < 2; ++u) {
            const int f = tid + 256 * u;
            const int row = f >> 3, dq = (f & 7) << 2;
            float4 v4 = *(const float4*)(base + (size_t)(kt * 64 + row) * 768 + 512 + h * 32 + dq);
            *(float4*)&Vs[row][dq] = v4;
        }
        __syncthreads();
        #pragma unroll 8
        for (int k = 0; k < 64; ++k) {
            const float p = Sb[pty][kt * 64 + k];
            float4 v4 = *(const float4*)&Vs[k][ptx << 2];
            cacc.x += p * v4.x; cacc.y += p * v4.y;
            cacc.z += p * v4.z; cacc.w += p * v4.w;
        }
        __syncthreads();
    }
    const float inv = 1.0f / rowsum[pty];
    cacc.x *= inv; cacc.y *= inv; cacc.z *= inv; cacc.w *= inv;
    *(float4*)(ctx + (size_t)(b * NN_ + qt * 32 + pty) * D_ + h * 32 + (ptx << 2)) = cacc;
}

extern "C" void kernel_launch(void* const* d_in, const int* in_sizes, int n_in,
                              void* d_out, int out_size, void* d_ws, size_t ws_size,
                              hipStream_t stream) {
    const float* x      = (const float*)d_in[0];
    const int*   erows  = (const int*)d_in[1];
    const int*   ecols  = (const int*)d_in[2];
    const float* evals  = (const float*)d_in[3];
    const float* w_gcn  = (const float*)d_in[4];
    const float* in_w   = (const float*)d_in[5];
    const float* in_b   = (const float*)d_in[6];
    const float* outw   = (const float*)d_in[7];
    const float* outb   = (const float*)d_in[8];
    const float* w1     = (const float*)d_in[9];
    const float* b1     = (const float*)d_in[10];
    const float* w2     = (const float*)d_in[11];
    const float* b2     = (const float*)d_in[12];
    const float* bn1g = (const float*)d_in[15], *bn1b = (const float*)d_in[16];
    const float* bn1m = (const float*)d_in[17], *bn1v = (const float*)d_in[18];
    const float* bn2g = (const float*)d_in[19], *bn2b = (const float*)d_in[20];
    const float* bn2m = (const float*)d_in[21], *bn2v = (const float*)d_in[22];
    const float* bn3g = (const float*)d_in[23], *bn3b = (const float*)d_in[24];
    const float* bn3m = (const float*)d_in[25], *bn3v = (const float*)d_in[26];

    float* ws  = (float*)d_ws;
    float* hl  = ws;                      // 2,097,152 floats (reused as ctx)
    float* agg = ws + 2097152;            // 2,097,152 (reused as x2)
    float* x1  = ws + 4194304;            // 2,097,152
    float* qkv = ws + 6291456;            // 6,291,456
    float* h1  = ws + 12582912;           // 8,388,608
    float* ctxb = hl;
    float* x2   = agg;
    float* out  = (float*)d_out;

    dim3 blk(256);
    // 1. hl = x @ w_gcn^T
    gemm_bt<0><<<dim3(4, 64), blk, 0, stream>>>(x, w_gcn, nullptr, hl,
        NT_, D_, D_, nullptr, nullptr, nullptr, nullptr, nullptr);
    // 2. agg = segment_sum(vals * hl[cols])
    gcn_spmm<<<dim3(128), blk, 0, stream>>>(erows, ecols, evals, hl, agg);
    // 3. x1 = bn1(x + gelu(agg))
    fuse_gcn<<<dim3(2048), blk, 0, stream>>>(x, agg, x1, bn1g, bn1b, bn1m, bn1v);
    // 4. qkv = x1 @ in_proj_w^T + in_proj_b
    gemm_bt<0><<<dim3(12, 64), blk, 0, stream>>>(x1, in_w, in_b, qkv,
        NT_, 3 * D_, D_, nullptr, nullptr, nullptr, nullptr, nullptr);
    // 5. attention -> ctx
    attn_fused<<<dim3(2048), blk, 0, stream>>>(qkv, ctxb);
    // 6. x2 = bn2(x1 + ctx @ out_proj_w^T + out_proj_b)
    gemm_bt<2><<<dim3(4, 64), blk, 0, stream>>>(ctxb, outw, outb, x2,
        NT_, D_, D_, x1, bn2g, bn2b, bn2m, bn2v);
    // 7. h1 = gelu(x2 @ w1^T + b1)
    gemm_bt<1><<<dim3(16, 64), blk, 0, stream>>>(x2, w1, b1, h1,
        NT_, 4 * D_, D_, nullptr, nullptr, nullptr, nullptr, nullptr);
    // 8. out = bn3(x2 + h1 @ w2^T + b2)
    gemm_bt<2><<<dim3(4, 64), blk, 0, stream>>>(h1, w2, b2, out,
        NT_, D_, 4 * D_, x2, bn3g, bn3b, bn3m, bn3v);
}

// Round 2
// 926.304 us; speedup vs baseline: 1.3350x; 1.3350x over previous
//
#include <hip/hip_runtime.h>
#include <hip/hip_bf16.h>
#include <math.h>

#define D_    256
#define NT_   8192
#define NN_   512
#define B_    16
#define H_    8
#define DH_   32
#define EPG_  16384
#define ECH   2048
#define BN_EPS 1e-5f

__device__ __forceinline__ float gelu_exact(float x) {
    return 0.5f * x * (1.0f + erff(x * 0.70710678118654752f));
}

// ---------------- GEMM: C = A(MxK) @ B(NxK)^T (+bias) (+epilogue) ----------
// EPI: 0 = none, 1 = gelu, 2 = resid + batchnorm
template<int EPI>
__global__ __launch_bounds__(256)
void gemm_bt(const float* __restrict__ A, const float* __restrict__ Bw,
             const float* __restrict__ bias, float* __restrict__ C,
             int M, int N, int K,
             const float* __restrict__ resid,
             const float* __restrict__ bng, const float* __restrict__ bnb,
             const float* __restrict__ bnm, const float* __restrict__ bnv)
{
    __shared__ float As[16][128];
    __shared__ float Bs[16][64];
    const int bm = blockIdx.y * 128;
    const int bn = blockIdx.x * 64;
    const int tid = threadIdx.x;
    const int tx = tid & 15;          // 4 output cols
    const int ty = tid >> 4;          // 8 output rows
    const int alm = tid >> 1, alk = (tid & 1) << 3;
    const int blm = tid >> 2, blk_ = (tid & 3) << 2;
    float acc[8][4] = {};
    for (int k0 = 0; k0 < K; k0 += 16) {
        #pragma unroll
        for (int u = 0; u < 2; ++u) {
            float4 a4 = *(const float4*)(A + (size_t)(bm + alm) * K + k0 + alk + u * 4);
            As[alk + u * 4 + 0][alm] = a4.x;
            As[alk + u * 4 + 1][alm] = a4.y;
            As[alk + u * 4 + 2][alm] = a4.z;
            As[alk + u * 4 + 3][alm] = a4.w;
        }
        {
            float4 b4 = *(const float4*)(Bw + (size_t)(bn + blm) * K + k0 + blk_);
            Bs[blk_ + 0][blm] = b4.x; Bs[blk_ + 1][blm] = b4.y;
            Bs[blk_ + 2][blm] = b4.z; Bs[blk_ + 3][blm] = b4.w;
        }
        __syncthreads();
        #pragma unroll
        for (int k = 0; k < 16; ++k) {
            float a[8], b[4];
            *(float4*)&a[0] = *(const float4*)&As[k][ty * 8];
            *(float4*)&a[4] = *(const float4*)&As[k][ty * 8 + 4];
            *(float4*)&b[0] = *(const float4*)&Bs[k][tx * 4];
            #pragma unroll
            for (int i = 0; i < 8; ++i)
                #pragma unroll
                for (int j = 0; j < 4; ++j)
                    acc[i][j] += a[i] * b[j];
        }
        __syncthreads();
    }
    #pragma unroll
    for (int i = 0; i < 8; ++i) {
        const int m = bm + ty * 8 + i;
        float4 o;
        float* op = &o.x;
        #pragma unroll
        for (int j = 0; j < 4; ++j) {
            const int n = bn + tx * 4 + j;
            float v = acc[i][j];
            if (bias) v += bias[n];
            if (EPI == 1) v = gelu_exact(v);
            if (EPI == 2) {
                v += resid[(size_t)m * N + n];
                v = (v - bnm[n]) * (bng[n] * rsqrtf(bnv[n] + BN_EPS)) + bnb[n];
            }
            op[j] = v;
        }
        *(float4*)(C + (size_t)m * N + bn + tx * 4) = o;
    }
}

// ---------------- GCN SpMM: per (graph, 16-dim chunk) block ----------------
// LDS-staged edge metadata + 16-deep unrolled gathers (ILP) + LDS accumulate.
__global__ __launch_bounds__(256)
void gcn_spmm(const int* __restrict__ rows, const int* __restrict__ cols,
              const float* __restrict__ vals, const float* __restrict__ hl,
              float* __restrict__ agg)
{
    const int b  = blockIdx.x >> 4;          // graph
    const int dc = (blockIdx.x & 15) << 4;   // 16-dim chunk base
    __shared__ float acc[NN_][16];           // 32 KiB
    __shared__ int   srow[ECH];              // 8 KiB
    __shared__ int   scol[ECH];              // 8 KiB
    __shared__ float sval[ECH];              // 8 KiB  (total 56 KiB)
    const int tid = threadIdx.x;
    float* accf = &acc[0][0];
    for (int i = tid; i < NN_ * 16 / 4; i += 256)
        *(float4*)&accf[i * 4] = make_float4(0.f, 0.f, 0.f, 0.f);
    const int grp = tid >> 4;      // 16 groups of 16 lanes
    const int d   = tid & 15;
    const int ebase = b * EPG_;
    for (int c0 = 0; c0 < EPG_; c0 += ECH) {
        __syncthreads();   // acc init done / previous chunk's readers done
        for (int i = tid; i < ECH; i += 256) {
            srow[i] = rows[ebase + c0 + i] - b * NN_;
            scol[i] = cols[ebase + c0 + i];
            sval[i] = vals[ebase + c0 + i];
        }
        __syncthreads();
        const int eg = grp * (ECH / 16);     // 128 edges per group
        #pragma unroll 1
        for (int e0 = 0; e0 < ECH / 16; e0 += 16) {
            float hv[16], v[16];
            int r[16];
            #pragma unroll
            for (int u = 0; u < 16; ++u) {
                const int e = eg + e0 + u;
                r[u] = srow[e];
                v[u] = sval[e];
                hv[u] = hl[(size_t)scol[e] * D_ + dc + d];   // 64B coalesced
            }
            #pragma unroll
            for (int u = 0; u < 16; ++u)
                atomicAdd(&acc[r[u]][d], v[u] * hv[u]);
        }
    }
    __syncthreads();
    for (int i = tid; i < NN_ * 16 / 4; i += 256) {
        const int r  = (i * 4) >> 4;
        const int dd = (i * 4) & 15;
        *(float4*)(agg + (size_t)(b * NN_ + r) * D_ + dc + dd) = *(const float4*)&accf[i * 4];
    }
}

// ---------------- x1 = bn1(x + gelu(agg)) ----------------------------------
__global__ __launch_bounds__(256)
void fuse_gcn(const float* __restrict__ x, const float* __restrict__ agg,
              float* __restrict__ x1,
              const float* __restrict__ g, const float* __restrict__ bb,
              const float* __restrict__ m, const float* __restrict__ v)
{
    const int i = blockIdx.x * 256 + threadIdx.x;   // float4 index
    const int d0 = (i & 63) << 2;
    float4 a4 = *(const float4*)(agg + (size_t)i * 4);
    float4 x4 = *(const float4*)(x + (size_t)i * 4);
    float av[4] = {a4.x, a4.y, a4.z, a4.w};
    float xv[4] = {x4.x, x4.y, x4.z, x4.w};
    float4 o;
    float* op = &o.x;
    #pragma unroll
    for (int j = 0; j < 4; ++j) {
        const int dd = d0 + j;
        const float t = xv[j] + gelu_exact(av[j]);
        op[j] = (t - m[dd]) * (g[dd] * rsqrtf(v[dd] + BN_EPS)) + bb[dd];
    }
    *(float4*)(x1 + (size_t)i * 4) = o;
}

// ---------------- fused attention: per (b, h, 32-row q-tile) ----------------
__global__ __launch_bounds__(256)
void attn_fused(const float* __restrict__ qkv, float* __restrict__ ctx)
{
    const int qt = blockIdx.x & 15;
    const int bh = blockIdx.x >> 4;
    const int b = bh >> 3, h = bh & 7;
    __shared__ float Sb[32][520];    // score rows (padded)
    __shared__ float Qt_[32][33];    // d-major Q tile
    __shared__ float Kt_[32][64];    // d-major K tile
    __shared__ float Vs[64][36];     // row-major V tile (padded)
    __shared__ float red[32][8];
    __shared__ float rowsum[32];
    __shared__ float rowmax[32];
    const int tid = threadIdx.x;
    const float scale = 0.17677669529663687f;   // 1/sqrt(32)
    const float* base = qkv + (size_t)b * NN_ * 768;

    {   // load Q tile transposed
        const int row = tid >> 3, dq = (tid & 7) << 2;
        float4 q4 = *(const float4*)(base + (size_t)(qt * 32 + row) * 768 + h * 32 + dq);
        Qt_[dq + 0][row] = q4.x; Qt_[dq + 1][row] = q4.y;
        Qt_[dq + 2][row] = q4.z; Qt_[dq + 3][row] = q4.w;
    }
    __syncthreads();

    const int tx = tid & 15, ty = tid >> 4;
    for (int kt = 0; kt < 8; ++kt) {
        #pragma unroll
        for (int u = 0; u < 2; ++u) {
            const int f = tid + 256 * u;
            const int row = f >> 3, dq = (f & 7) << 2;
            float4 k4 = *(const float4*)(base + (size_t)(kt * 64 + row) * 768 + 256 + h * 32 + dq);
            Kt_[dq + 0][row] = k4.x; Kt_[dq + 1][row] = k4.y;
            Kt_[dq + 2][row] = k4.z; Kt_[dq + 3][row] = k4.w;
        }
        __syncthreads();
        float acc[2][4] = {};
        #pragma unroll
        for (int dd = 0; dd < 32; ++dd) {
            const float q0 = Qt_[dd][ty];
            const float q1 = Qt_[dd][ty + 16];
            float4 kv = *(const float4*)&Kt_[dd][tx << 2];
            float kk[4] = {kv.x, kv.y, kv.z, kv.w};
            #pragma unroll
            for (int j = 0; j < 4; ++j) {
                acc[0][j] += q0 * kk[j];
                acc[1][j] += q1 * kk[j];
            }
        }
        #pragma unroll
        for (int i = 0; i < 2; ++i) {
            float4 s4 = make_float4(acc[i][0] * scale, acc[i][1] * scale,
                                    acc[i][2] * scale, acc[i][3] * scale);
            *(float4*)&Sb[ty + 16 * i][kt * 64 + (tx << 2)] = s4;
        }
        __syncthreads();
    }

    {   // softmax: unnormalized exp, keep row sums
        const int row = tid >> 3, sub = tid & 7;
        float mx = -1e30f;
        for (int c = sub * 64; c < sub * 64 + 64; c += 4) {
            float4 s4 = *(const float4*)&Sb[row][c];
            mx = fmaxf(mx, fmaxf(fmaxf(s4.x, s4.y), fmaxf(s4.z, s4.w)));
        }
        red[row][sub] = mx;
        __syncthreads();
        if (sub == 0) {
            float m2 = red[row][0];
            #pragma unroll
            for (int t = 1; t < 8; ++t) m2 = fmaxf(m2, red[row][t]);
            rowmax[row] = m2;
        }
        __syncthreads();
        const float M = rowmax[row];
        float sum = 0.f;
        for (int c = sub * 64; c < sub * 64 + 64; c += 4) {
            float4 s4 = *(const float4*)&Sb[row][c];
            s4.x = __expf(s4.x - M); s4.y = __expf(s4.y - M);
            s4.z = __expf(s4.z - M); s4.w = __expf(s4.w - M);
            sum += s4.x + s4.y + s4.z + s4.w;
            *(float4*)&Sb[row][c] = s4;
        }
        red[row][sub] = sum;
        __syncthreads();
        if (sub == 0) {
            float s2 = 0.f;
            #pragma unroll
            for (int t = 0; t < 8; ++t) s2 += red[row][t];
            rowsum[row] = s2;
        }
        __syncthreads();
    }

    // PV
    const int ptx = tid & 7, pty = tid >> 3;
    float4 cacc = make_float4(0.f, 0.f, 0.f, 0.f);
    for (int kt = 0; kt < 8; ++kt) {
        #pragma unroll
        for (int u = 0; u < 2; ++u) {
            const int f = tid + 256 * u;
            const int row = f >> 3, dq = (f & 7) << 2;
            float4 v4 = *(const float4*)(base + (size_t)(kt * 64 + row) * 768 + 512 + h * 32 + dq);
            *(float4*)&Vs[row][dq] = v4;
        }
        __syncthreads();
        #pragma unroll 8
        for (int k = 0; k < 64; ++k) {
            const float p = Sb[pty][kt * 64 + k];
            float4 v4 = *(const float4*)&Vs[k][ptx << 2];
            cacc.x += p * v4.x; cacc.y += p * v4.y;
            cacc.z += p * v4.z; cacc.w += p * v4.w;
        }
        __syncthreads();
    }
    const float inv = 1.0f / rowsum[pty];
    cacc.x *= inv; cacc.y *= inv; cacc.z *= inv; cacc.w *= inv;
    *(float4*)(ctx + (size_t)(b * NN_ + qt * 32 + pty) * D_ + h * 32 + (ptx << 2)) = cacc;
}

extern "C" void kernel_launch(void* const* d_in, const int* in_sizes, int n_in,
                              void* d_out, int out_size, void* d_ws, size_t ws_size,
                              hipStream_t stream) {
    const float* x      = (const float*)d_in[0];
    const int*   erows  = (const int*)d_in[1];
    const int*   ecols  = (const int*)d_in[2];
    const float* evals  = (const float*)d_in[3];
    const float* w_gcn  = (const float*)d_in[4];
    const float* in_w   = (const float*)d_in[5];
    const float* in_b   = (const float*)d_in[6];
    const float* outw   = (const float*)d_in[7];
    const float* outb   = (const float*)d_in[8];
    const float* w1     = (const float*)d_in[9];
    const float* b1     = (const float*)d_in[10];
    const float* w2     = (const float*)d_in[11];
    const float* b2     = (const float*)d_in[12];
    const float* bn1g = (const float*)d_in[15], *bn1b = (const float*)d_in[16];
    const float* bn1m = (const float*)d_in[17], *bn1v = (const float*)d_in[18];
    const float* bn2g = (const float*)d_in[19], *bn2b = (const float*)d_in[20];
    const float* bn2m = (const float*)d_in[21], *bn2v = (const float*)d_in[22];
    const float* bn3g = (const float*)d_in[23], *bn3b = (const float*)d_in[24];
    const float* bn3m = (const float*)d_in[25], *bn3v = (const float*)d_in[26];

    float* ws  = (float*)d_ws;
    float* hl  = ws;                      // 2,097,152 floats (reused as ctx)
    float* agg = ws + 2097152;            // 2,097,152 (reused as x2)
    float* x1  = ws + 4194304;            // 2,097,152
    float* qkv = ws + 6291456;            // 6,291,456
    float* h1  = ws + 12582912;           // 8,388,608
    float* ctxb = hl;
    float* x2   = agg;
    float* out  = (float*)d_out;

    dim3 blk(256);
    // 1. hl = x @ w_gcn^T
    gemm_bt<0><<<dim3(4, 64), blk, 0, stream>>>(x, w_gcn, nullptr, hl,
        NT_, D_, D_, nullptr, nullptr, nullptr, nullptr, nullptr);
    // 2. agg = segment_sum(vals * hl[cols])   (256 blocks: 16 graphs x 16 chunks)
    gcn_spmm<<<dim3(256), blk, 0, stream>>>(erows, ecols, evals, hl, agg);
    // 3. x1 = bn1(x + gelu(agg))
    fuse_gcn<<<dim3(2048), blk, 0, stream>>>(x, agg, x1, bn1g, bn1b, bn1m, bn1v);
    // 4. qkv = x1 @ in_proj_w^T + in_proj_b
    gemm_bt<0><<<dim3(12, 64), blk, 0, stream>>>(x1, in_w, in_b, qkv,
        NT_, 3 * D_, D_, nullptr, nullptr, nullptr, nullptr, nullptr);
    // 5. attention -> ctx
    attn_fused<<<dim3(2048), blk, 0, stream>>>(qkv, ctxb);
    // 6. x2 = bn2(x1 + ctx @ out_proj_w^T + out_proj_b)
    gemm_bt<2><<<dim3(4, 64), blk, 0, stream>>>(ctxb, outw, outb, x2,
        NT_, D_, D_, x1, bn2g, bn2b, bn2m, bn2v);
    // 7. h1 = gelu(x2 @ w1^T + b1)
    gemm_bt<1><<<dim3(16, 64), blk, 0, stream>>>(x2, w1, b1, h1,
        NT_, 4 * D_, D_, nullptr, nullptr, nullptr, nullptr, nullptr);
    // 8. out = bn3(x2 + h1 @ w2^T + b2)
    gemm_bt<2><<<dim3(4, 64), blk, 0, stream>>>(h1, w2, b2, out,
        NT_, D_, 4 * D_, x2, bn3g, bn3b, bn3m, bn3v);
}

// Round 4
// 495.981 us; speedup vs baseline: 2.4934x; 1.8676x over previous
//
#include <hip/hip_runtime.h>
#include <hip/hip_bf16.h>
#include <math.h>

#define D_    256
#define NT_   8192
#define NN_   512
#define B_    16
#define H_    8
#define EPG_  16384
#define BN_EPS 1e-5f

typedef __attribute__((ext_vector_type(8))) short bx8;
typedef __attribute__((ext_vector_type(4))) float fx4;

__device__ __forceinline__ float gelu_exact(float x) {
    return 0.5f * x * (1.0f + erff(x * 0.70710678118654752f));
}

// ============ bf16 MFMA GEMM: C = A(MxK) @ B(NxK)^T (+bias)(+epi) =========
// A,B bf16 (as short). EPI: 0 none, 1 gelu, 2 resid+BN, 3 resid+gelu(acc)+BN
// OBF: output bf16 (else f32). RBF: resid bf16 (else f32).
template<int EPI, int OBF, int RBF>
__global__ __launch_bounds__(256)
void mgemm(const short* __restrict__ A, const short* __restrict__ Bw,
           const float* __restrict__ bias, void* __restrict__ Cout,
           int M, int N, int K,
           long sA, long sB, long sC, long sR,
           const void* __restrict__ resid,
           const float* __restrict__ bng, const float* __restrict__ bnb,
           const float* __restrict__ bnm, const float* __restrict__ bnv)
{
    __shared__ short As[128][32];
    __shared__ short Bs[128][32];
    const int bz = blockIdx.z;
    A  += (size_t)bz * sA;
    Bw += (size_t)bz * sB;
    const int bm = blockIdx.y * 128, bn = blockIdx.x * 128;
    const int tid = threadIdx.x;
    const int w = tid >> 6, lane = tid & 63;
    const int wm = w >> 1, wn = w & 1;            // wave -> 64x64 quadrant
    const int strow = tid >> 1, stc = (tid & 1) << 4;  // staging: row, col(16)
    const int fr = lane & 15, fk = (lane >> 4) << 3;   // fragment row/k
    fx4 acc[4][4] = {};

    for (int k0 = 0; k0 < K; k0 += 32) {
        bx8 a0 = *(const bx8*)(A  + (size_t)(bm + strow) * K + k0 + stc);
        bx8 a1 = *(const bx8*)(A  + (size_t)(bm + strow) * K + k0 + stc + 8);
        bx8 b0 = *(const bx8*)(Bw + (size_t)(bn + strow) * K + k0 + stc);
        bx8 b1 = *(const bx8*)(Bw + (size_t)(bn + strow) * K + k0 + stc + 8);
        __syncthreads();   // previous compute done before overwrite
        *(bx8*)&As[strow][stc]     = a0;
        *(bx8*)&As[strow][stc + 8] = a1;
        *(bx8*)&Bs[strow][stc]     = b0;
        *(bx8*)&Bs[strow][stc + 8] = b1;
        __syncthreads();
        bx8 af[4], bf[4];
        #pragma unroll
        for (int m = 0; m < 4; ++m) af[m] = *(const bx8*)&As[wm * 64 + m * 16 + fr][fk];
        #pragma unroll
        for (int n = 0; n < 4; ++n) bf[n] = *(const bx8*)&Bs[wn * 64 + n * 16 + fr][fk];
        #pragma unroll
        for (int m = 0; m < 4; ++m)
            #pragma unroll
            for (int n = 0; n < 4; ++n)
                acc[m][n] = __builtin_amdgcn_mfma_f32_16x16x32_bf16(af[m], bf[n], acc[m][n], 0, 0, 0);
    }

    float* Cf = (float*)Cout + (size_t)bz * sC;
    __hip_bfloat16* Cb = (__hip_bfloat16*)Cout + (size_t)bz * sC;
    const float* Rf = (const float*)resid + (EPI >= 2 ? (size_t)bz * sR : 0);
    const __hip_bfloat16* Rb = (const __hip_bfloat16*)resid + (EPI >= 2 ? (size_t)bz * sR : 0);
    #pragma unroll
    for (int m = 0; m < 4; ++m) {
        #pragma unroll
        for (int n = 0; n < 4; ++n) {
            #pragma unroll
            for (int r = 0; r < 4; ++r) {
                const int gm = bm + wm * 64 + m * 16 + (lane >> 4) * 4 + r;
                const int gn = bn + wn * 64 + n * 16 + fr;
                float v = acc[m][n][r];
                if (bias) v += bias[gn];
                if (EPI == 1) v = gelu_exact(v);
                if (EPI == 2 || EPI == 3) {
                    const float rv = RBF ? __bfloat162float(Rb[(size_t)gm * N + gn])
                                         : Rf[(size_t)gm * N + gn];
                    if (EPI == 2) v += rv;
                    else          v = rv + gelu_exact(v);
                    v = (v - bnm[gn]) * (bng[gn] * rsqrtf(bnv[gn] + BN_EPS)) + bnb[gn];
                }
                if (OBF) Cb[(size_t)gm * N + gn] = __float2bfloat16(v);
                else     Cf[(size_t)gm * N + gn] = v;
            }
        }
    }
}

// ============ converts ======================================================
__device__ __forceinline__ void cv4(const float4 v, __hip_bfloat16* d) {
    __hip_bfloat162* dp = (__hip_bfloat162*)d;
    dp[0] = __hip_bfloat162(__float2bfloat16(v.x), __float2bfloat16(v.y));
    dp[1] = __hip_bfloat162(__float2bfloat16(v.z), __float2bfloat16(v.w));
}

__global__ __launch_bounds__(256)
void conv6(const float* __restrict__ x,  const float* __restrict__ wg,
           const float* __restrict__ iw, const float* __restrict__ ow,
           const float* __restrict__ w1, const float* __restrict__ w2,
           __hip_bfloat16* xb, __hip_bfloat16* wgb, __hip_bfloat16* iwb,
           __hip_bfloat16* owb, __hip_bfloat16* w1b, __hip_bfloat16* w2b)
{
    int i = blockIdx.x * 256 + threadIdx.x;   // float4 index
    const float* s; __hip_bfloat16* d; int o;
    if      (i < 524288) { s = x;  d = xb;  o = i; }
    else if (i < 540672) { s = wg; d = wgb; o = i - 524288; }
    else if (i < 589824) { s = iw; d = iwb; o = i - 540672; }
    else if (i < 606208) { s = ow; d = owb; o = i - 589824; }
    else if (i < 671744) { s = w1; d = w1b; o = i - 606208; }
    else                 { s = w2; d = w2b; o = i - 671744; }
    cv4(((const float4*)s)[o], d + (size_t)o * 4);
}

__global__ __launch_bounds__(256)
void convA(const float* __restrict__ s, __hip_bfloat16* __restrict__ d, int n4)
{
    int i = blockIdx.x * 256 + threadIdx.x;
    if (i >= n4) return;
    cv4(((const float4*)s)[i], d + (size_t)i * 4);
}

// ============ dense adjacency build ========================================
__global__ __launch_bounds__(256)
void build_S(const int* __restrict__ rows, const int* __restrict__ cols,
             const float* __restrict__ vals, float* __restrict__ SA)
{
    const int e = blockIdx.x * 256 + threadIdx.x;   // 262144 edges
    const int r = rows[e], c = cols[e];
    const int g = r >> 9;
    atomicAdd(&SA[((size_t)g << 18) + (size_t)(r & 511) * 512 + (c - (g << 9))], vals[e]);
}

// ============ transpose hl (8192x256) -> hlB[g][256][512] ==================
// 64x64 tile per block; 256 threads handle 2 rows each (load + store phases).
__global__ __launch_bounds__(256)
void transp(const __hip_bfloat16* __restrict__ hl, __hip_bfloat16* __restrict__ hlB)
{
    __shared__ short T[64][72];
    const int nt = blockIdx.x, it = blockIdx.y, g = blockIdx.z;
    const int r0 = threadIdx.x >> 3, c8 = (threadIdx.x & 7) << 3;  // r0 in [0,32)
    #pragma unroll
    for (int u = 0; u < 2; ++u) {
        const int r = r0 + u * 32;   // k-row within tile
        *(bx8*)&T[r][c8] = *(const bx8*)&hl[(size_t)(g * 512 + it * 64 + r) * 256 + nt * 64 + c8];
    }
    __syncthreads();
    #pragma unroll
    for (int u = 0; u < 2; ++u) {
        const int r = r0 + u * 32;   // n-row of output
        bx8 o;
        #pragma unroll
        for (int j = 0; j < 8; ++j) o[j] = T[c8 + j][r];
        *(bx8*)&hlB[((size_t)(g * 256 + nt * 64 + r)) * 512 + it * 64 + c8] = o;
    }
}

// ============ fused attention (fp32, bf16 out) =============================
__global__ __launch_bounds__(256)
void attn_fused(const float* __restrict__ qkv, __hip_bfloat16* __restrict__ ctx)
{
    const int qt = blockIdx.x & 15;
    const int bh = blockIdx.x >> 4;
    const int b = bh >> 3, h = bh & 7;
    __shared__ float Sb[32][520];
    __shared__ float Qt_[32][33];
    __shared__ float Kt_[32][64];
    __shared__ float Vs[64][36];
    __shared__ float red[32][8];
    __shared__ float rowsum[32];
    __shared__ float rowmax[32];
    const int tid = threadIdx.x;
    const float scale = 0.17677669529663687f;
    const float* base = qkv + (size_t)b * NN_ * 768;

    {
        const int row = tid >> 3, dq = (tid & 7) << 2;
        float4 q4 = *(const float4*)(base + (size_t)(qt * 32 + row) * 768 + h * 32 + dq);
        Qt_[dq + 0][row] = q4.x; Qt_[dq + 1][row] = q4.y;
        Qt_[dq + 2][row] = q4.z; Qt_[dq + 3][row] = q4.w;
    }
    __syncthreads();

    const int tx = tid & 15, ty = tid >> 4;
    for (int kt = 0; kt < 8; ++kt) {
        #pragma unroll
        for (int u = 0; u < 2; ++u) {
            const int f = tid + 256 * u;
            const int row = f >> 3, dq = (f & 7) << 2;
            float4 k4 = *(const float4*)(base + (size_t)(kt * 64 + row) * 768 + 256 + h * 32 + dq);
            Kt_[dq + 0][row] = k4.x; Kt_[dq + 1][row] = k4.y;
            Kt_[dq + 2][row] = k4.z; Kt_[dq + 3][row] = k4.w;
        }
        __syncthreads();
        float acc[2][4] = {};
        #pragma unroll
        for (int dd = 0; dd < 32; ++dd) {
            const float q0 = Qt_[dd][ty];
            const float q1 = Qt_[dd][ty + 16];
            float4 kv = *(const float4*)&Kt_[dd][tx << 2];
            float kk[4] = {kv.x, kv.y, kv.z, kv.w};
            #pragma unroll
            for (int j = 0; j < 4; ++j) {
                acc[0][j] += q0 * kk[j];
                acc[1][j] += q1 * kk[j];
            }
        }
        #pragma unroll
        for (int i = 0; i < 2; ++i) {
            float4 s4 = make_float4(acc[i][0] * scale, acc[i][1] * scale,
                                    acc[i][2] * scale, acc[i][3] * scale);
            *(float4*)&Sb[ty + 16 * i][kt * 64 + (tx << 2)] = s4;
        }
        __syncthreads();
    }

    {
        const int row = tid >> 3, sub = tid & 7;
        float mx = -1e30f;
        for (int c = sub * 64; c < sub * 64 + 64; c += 4) {
            float4 s4 = *(const float4*)&Sb[row][c];
            mx = fmaxf(mx, fmaxf(fmaxf(s4.x, s4.y), fmaxf(s4.z, s4.w)));
        }
        red[row][sub] = mx;
        __syncthreads();
        if (sub == 0) {
            float m2 = red[row][0];
            #pragma unroll
            for (int t = 1; t < 8; ++t) m2 = fmaxf(m2, red[row][t]);
            rowmax[row] = m2;
        }
        __syncthreads();
        const float M = rowmax[row];
        float sum = 0.f;
        for (int c = sub * 64; c < sub * 64 + 64; c += 4) {
            float4 s4 = *(const float4*)&Sb[row][c];
            s4.x = __expf(s4.x - M); s4.y = __expf(s4.y - M);
            s4.z = __expf(s4.z - M); s4.w = __expf(s4.w - M);
            sum += s4.x + s4.y + s4.z + s4.w;
            *(float4*)&Sb[row][c] = s4;
        }
        red[row][sub] = sum;
        __syncthreads();
        if (sub == 0) {
            float s2 = 0.f;
            #pragma unroll
            for (int t = 0; t < 8; ++t) s2 += red[row][t];
            rowsum[row] = s2;
        }
        __syncthreads();
    }

    const int ptx = tid & 7, pty = tid >> 3;
    float4 cacc = make_float4(0.f, 0.f, 0.f, 0.f);
    for (int kt = 0; kt < 8; ++kt) {
        #pragma unroll
        for (int u = 0; u < 2; ++u) {
            const int f = tid + 256 * u;
            const int row = f >> 3, dq = (f & 7) << 2;
            float4 v4 = *(const float4*)(base + (size_t)(kt * 64 + row) * 768 + 512 + h * 32 + dq);
            *(float4*)&Vs[row][dq] = v4;
        }
        __syncthreads();
        #pragma unroll 8
        for (int k = 0; k < 64; ++k) {
            const float p = Sb[pty][kt * 64 + k];
            float4 v4 = *(const float4*)&Vs[k][ptx << 2];
            cacc.x += p * v4.x; cacc.y += p * v4.y;
            cacc.z += p * v4.z; cacc.w += p * v4.w;
        }
        __syncthreads();
    }
    const float inv = 1.0f / rowsum[pty];
    __hip_bfloat162* cp = (__hip_bfloat162*)&ctx[(size_t)(b * NN_ + qt * 32 + pty) * D_ + h * 32 + (ptx << 2)];
    cp[0] = __hip_bfloat162(__float2bfloat16(cacc.x * inv), __float2bfloat16(cacc.y * inv));
    cp[1] = __hip_bfloat162(__float2bfloat16(cacc.z * inv), __float2bfloat16(cacc.w * inv));
}

extern "C" void kernel_launch(void* const* d_in, const int* in_sizes, int n_in,
                              void* d_out, int out_size, void* d_ws, size_t ws_size,
                              hipStream_t stream) {
    const float* x      = (const float*)d_in[0];
    const int*   erows  = (const int*)d_in[1];
    const int*   ecols  = (const int*)d_in[2];
    const float* evals  = (const float*)d_in[3];
    const float* w_gcn  = (const float*)d_in[4];
    const float* in_w   = (const float*)d_in[5];
    const float* in_b   = (const float*)d_in[6];
    const float* outw   = (const float*)d_in[7];
    const float* outb   = (const float*)d_in[8];
    const float* w1     = (const float*)d_in[9];
    const float* b1     = (const float*)d_in[10];
    const float* w2     = (const float*)d_in[11];
    const float* b2     = (const float*)d_in[12];
    const float* bn1g = (const float*)d_in[15], *bn1b = (const float*)d_in[16];
    const float* bn1m = (const float*)d_in[17], *bn1v = (const float*)d_in[18];
    const float* bn2g = (const float*)d_in[19], *bn2b = (const float*)d_in[20];
    const float* bn2m = (const float*)d_in[21], *bn2v = (const float*)d_in[22];
    const float* bn3g = (const float*)d_in[23], *bn3b = (const float*)d_in[24];
    const float* bn3m = (const float*)d_in[25], *bn3v = (const float*)d_in[26];

    short* wsS = (short*)d_ws;
    __hip_bfloat16* xb    = (__hip_bfloat16*)(wsS + 0);
    __hip_bfloat16* wgcnb = (__hip_bfloat16*)(wsS + 2097152);
    __hip_bfloat16* iwb   = (__hip_bfloat16*)(wsS + 2162688);
    __hip_bfloat16* owb   = (__hip_bfloat16*)(wsS + 2359296);
    __hip_bfloat16* w1b   = (__hip_bfloat16*)(wsS + 2424832);
    __hip_bfloat16* w2b   = (__hip_bfloat16*)(wsS + 2686976);
    short* hl   = wsS + 2949120;      // 8192x256 bf16
    short* hlB  = wsS + 5046272;      // 16 x 256 x 512 bf16
    short* x1b  = wsS + 7143424;      // 8192x256
    short* ctxb = wsS + 9240576;      // 8192x256
    short* x2b  = wsS + 11337728;     // 8192x256
    short* h1b  = wsS + 13434880;     // 8192x1024
    short* SAb  = wsS + 21823488;     // 16x512x512 bf16
    float* SA   = (float*)(wsS + 26017792);   // 16x512x512 f32 (dead after conv)
    float* qkv  = (float*)(wsS + 26017792);   // 8192x768 f32 (overlaps SA)
    float* out  = (float*)d_out;

    dim3 blk(256);
    // converts of static inputs
    conv6<<<dim3(2880), blk, 0, stream>>>(x, w_gcn, in_w, outw, w1, w2,
                                          xb, wgcnb, iwb, owb, w1b, w2b);
    // dense adjacency
    hipMemsetAsync(SA, 0, (size_t)16 * 512 * 512 * 4, stream);
    build_S<<<dim3(1024), blk, 0, stream>>>(erows, ecols, evals, SA);
    convA<<<dim3(4096), blk, 0, stream>>>(SA, (__hip_bfloat16*)SAb, 1048576);
    // 1. hl = xb @ wgcnb^T   (bf16 out)
    mgemm<0,1,0><<<dim3(2, 64, 1), blk, 0, stream>>>((const short*)xb, (const short*)wgcnb,
        nullptr, hl, NT_, D_, D_, 0,0,0,0, nullptr, nullptr, nullptr, nullptr, nullptr);
    // 2. transpose
    transp<<<dim3(4, 8, 16), blk, 0, stream>>>((const __hip_bfloat16*)hl, (__hip_bfloat16*)hlB);
    // 3. x1 = bn1(x + gelu(S @ hl))  batched per graph
    mgemm<3,1,0><<<dim3(2, 4, 16), blk, 0, stream>>>(SAb, hlB, nullptr, x1b,
        512, D_, 512, 262144, 131072, 131072, 131072,
        x, bn1g, bn1b, bn1m, bn1v);
    // 4. qkv = x1b @ iwb^T + in_b   (f32 out)
    mgemm<0,0,0><<<dim3(6, 64, 1), blk, 0, stream>>>(x1b, (const short*)iwb, in_b, qkv,
        NT_, 3 * D_, D_, 0,0,0,0, nullptr, nullptr, nullptr, nullptr, nullptr);
    // 5. attention -> ctx (bf16)
    attn_fused<<<dim3(2048), blk, 0, stream>>>(qkv, (__hip_bfloat16*)ctxb);
    // 6. x2 = bn2(x1 + ctx @ owb^T + outb)
    mgemm<2,1,1><<<dim3(2, 64, 1), blk, 0, stream>>>(ctxb, (const short*)owb, outb, x2b,
        NT_, D_, D_, 0,0,0,0, x1b, bn2g, bn2b, bn2m, bn2v);
    // 7. h1 = gelu(x2 @ w1b^T + b1)
    mgemm<1,1,0><<<dim3(8, 64, 1), blk, 0, stream>>>(x2b, (const short*)w1b, b1, h1b,
        NT_, 4 * D_, D_, 0,0,0,0, nullptr, nullptr, nullptr, nullptr, nullptr);
    // 8. out = bn3(x2 + h1 @ w2b^T + b2)   (f32 out)
    mgemm<2,0,1><<<dim3(2, 64, 1), blk, 0, stream>>>(h1b, (const short*)w2b, b2, out,
        NT_, D_, 4 * D_, 0,0,0,0, x2b, bn3g, bn3b, bn3m, bn3v);
}

// Round 5
// 327.240 us; speedup vs baseline: 3.7791x; 1.5157x over previous
//
#include <hip/hip_runtime.h>
#include <hip/hip_bf16.h>
#include <math.h>

#define D_    256
#define NT_   8192
#define NN_   512
#define B_    16
#define H_    8
#define EPG_  16384
#define BN_EPS 1e-5f

typedef __attribute__((ext_vector_type(8))) short bx8;
typedef __attribute__((ext_vector_type(4))) float fx4;

__device__ __forceinline__ float gelu_exact(float x) {
    return 0.5f * x * (1.0f + erff(x * 0.70710678118654752f));
}

// ============ bf16 MFMA GEMM: C = A(MxK) @ B(NxK)^T (+bias)(+epi) =========
// A,B bf16 (as short). EPI: 0 none, 1 gelu, 2 resid+BN, 3 resid+gelu(acc)+BN
// OBF: output bf16 (else f32). RBF: resid bf16 (else f32).
template<int EPI, int OBF, int RBF>
__global__ __launch_bounds__(256)
void mgemm(const short* __restrict__ A, const short* __restrict__ Bw,
           const float* __restrict__ bias, void* __restrict__ Cout,
           int M, int N, int K,
           long sA, long sB, long sC, long sR,
           const void* __restrict__ resid,
           const float* __restrict__ bng, const float* __restrict__ bnb,
           const float* __restrict__ bnm, const float* __restrict__ bnv)
{
    __shared__ short As[128][32];
    __shared__ short Bs[128][32];
    const int bz = blockIdx.z;
    A  += (size_t)bz * sA;
    Bw += (size_t)bz * sB;
    const int bm = blockIdx.y * 128, bn = blockIdx.x * 128;
    const int tid = threadIdx.x;
    const int w = tid >> 6, lane = tid & 63;
    const int wm = w >> 1, wn = w & 1;            // wave -> 64x64 quadrant
    const int strow = tid >> 1, stc = (tid & 1) << 4;  // staging: row, col(16)
    const int fr = lane & 15, fk = (lane >> 4) << 3;   // fragment row/k
    fx4 acc[4][4] = {};

    for (int k0 = 0; k0 < K; k0 += 32) {
        bx8 a0 = *(const bx8*)(A  + (size_t)(bm + strow) * K + k0 + stc);
        bx8 a1 = *(const bx8*)(A  + (size_t)(bm + strow) * K + k0 + stc + 8);
        bx8 b0 = *(const bx8*)(Bw + (size_t)(bn + strow) * K + k0 + stc);
        bx8 b1 = *(const bx8*)(Bw + (size_t)(bn + strow) * K + k0 + stc + 8);
        __syncthreads();   // previous compute done before overwrite
        *(bx8*)&As[strow][stc]     = a0;
        *(bx8*)&As[strow][stc + 8] = a1;
        *(bx8*)&Bs[strow][stc]     = b0;
        *(bx8*)&Bs[strow][stc + 8] = b1;
        __syncthreads();
        bx8 af[4], bf[4];
        #pragma unroll
        for (int m = 0; m < 4; ++m) af[m] = *(const bx8*)&As[wm * 64 + m * 16 + fr][fk];
        #pragma unroll
        for (int n = 0; n < 4; ++n) bf[n] = *(const bx8*)&Bs[wn * 64 + n * 16 + fr][fk];
        #pragma unroll
        for (int m = 0; m < 4; ++m)
            #pragma unroll
            for (int n = 0; n < 4; ++n)
                acc[m][n] = __builtin_amdgcn_mfma_f32_16x16x32_bf16(af[m], bf[n], acc[m][n], 0, 0, 0);
    }

    float* Cf = (float*)Cout + (size_t)bz * sC;
    __hip_bfloat16* Cb = (__hip_bfloat16*)Cout + (size_t)bz * sC;
    const float* Rf = (const float*)resid + (EPI >= 2 ? (size_t)bz * sR : 0);
    const __hip_bfloat16* Rb = (const __hip_bfloat16*)resid + (EPI >= 2 ? (size_t)bz * sR : 0);
    #pragma unroll
    for (int m = 0; m < 4; ++m) {
        #pragma unroll
        for (int n = 0; n < 4; ++n) {
            #pragma unroll
            for (int r = 0; r < 4; ++r) {
                const int gm = bm + wm * 64 + m * 16 + (lane >> 4) * 4 + r;
                const int gn = bn + wn * 64 + n * 16 + fr;
                float v = acc[m][n][r];
                if (bias) v += bias[gn];
                if (EPI == 1) v = gelu_exact(v);
                if (EPI == 2 || EPI == 3) {
                    const float rv = RBF ? __bfloat162float(Rb[(size_t)gm * N + gn])
                                         : Rf[(size_t)gm * N + gn];
                    if (EPI == 2) v += rv;
                    else          v = rv + gelu_exact(v);
                    v = (v - bnm[gn]) * (bng[gn] * rsqrtf(bnv[gn] + BN_EPS)) + bnb[gn];
                }
                if (OBF) Cb[(size_t)gm * N + gn] = __float2bfloat16(v);
                else     Cf[(size_t)gm * N + gn] = v;
            }
        }
    }
}

// ============ converts ======================================================
__device__ __forceinline__ void cv4(const float4 v, __hip_bfloat16* d) {
    __hip_bfloat162* dp = (__hip_bfloat162*)d;
    dp[0] = __hip_bfloat162(__float2bfloat16(v.x), __float2bfloat16(v.y));
    dp[1] = __hip_bfloat162(__float2bfloat16(v.z), __float2bfloat16(v.w));
}

__global__ __launch_bounds__(256)
void conv6(const float* __restrict__ x,  const float* __restrict__ wg,
           const float* __restrict__ iw, const float* __restrict__ ow,
           const float* __restrict__ w1, const float* __restrict__ w2,
           __hip_bfloat16* xb, __hip_bfloat16* wgb, __hip_bfloat16* iwb,
           __hip_bfloat16* owb, __hip_bfloat16* w1b, __hip_bfloat16* w2b)
{
    int i = blockIdx.x * 256 + threadIdx.x;   // float4 index
    const float* s; __hip_bfloat16* d; int o;
    if      (i < 524288) { s = x;  d = xb;  o = i; }
    else if (i < 540672) { s = wg; d = wgb; o = i - 524288; }
    else if (i < 589824) { s = iw; d = iwb; o = i - 540672; }
    else if (i < 606208) { s = ow; d = owb; o = i - 589824; }
    else if (i < 671744) { s = w1; d = w1b; o = i - 606208; }
    else                 { s = w2; d = w2b; o = i - 671744; }
    cv4(((const float4*)s)[o], d + (size_t)o * 4);
}

__global__ __launch_bounds__(256)
void convA(const float* __restrict__ s, __hip_bfloat16* __restrict__ d, int n4)
{
    int i = blockIdx.x * 256 + threadIdx.x;
    if (i >= n4) return;
    cv4(((const float4*)s)[i], d + (size_t)i * 4);
}

// ============ dense adjacency build ========================================
__global__ __launch_bounds__(256)
void build_S(const int* __restrict__ rows, const int* __restrict__ cols,
             const float* __restrict__ vals, float* __restrict__ SA)
{
    const int e = blockIdx.x * 256 + threadIdx.x;   // 262144 edges
    const int r = rows[e], c = cols[e];
    const int g = r >> 9;
    atomicAdd(&SA[((size_t)g << 18) + (size_t)(r & 511) * 512 + (c - (g << 9))], vals[e]);
}

// ============ transpose hl (8192x256) -> hlB[g][256][512] ==================
// 64x64 tile per block; 256 threads handle 2 rows each (load + store phases).
__global__ __launch_bounds__(256)
void transp(const __hip_bfloat16* __restrict__ hl, __hip_bfloat16* __restrict__ hlB)
{
    __shared__ short T[64][72];
    const int nt = blockIdx.x, it = blockIdx.y, g = blockIdx.z;
    const int r0 = threadIdx.x >> 3, c8 = (threadIdx.x & 7) << 3;  // r0 in [0,32)
    #pragma unroll
    for (int u = 0; u < 2; ++u) {
        const int r = r0 + u * 32;   // k-row within tile
        *(bx8*)&T[r][c8] = *(const bx8*)&hl[(size_t)(g * 512 + it * 64 + r) * 256 + nt * 64 + c8];
    }
    __syncthreads();
    #pragma unroll
    for (int u = 0; u < 2; ++u) {
        const int r = r0 + u * 32;   // n-row of output
        bx8 o;
        #pragma unroll
        for (int j = 0; j < 8; ++j) o[j] = T[c8 + j][r];
        *(bx8*)&hlB[((size_t)(g * 256 + nt * 64 + r)) * 512 + it * 64 + c8] = o;
    }
}

// ============ MFMA flash attention: block = (b, h, 64 q-rows) ==============
// qkv bf16 [8192][768]. K staged [512][40] (pad->2-way banks), V transposed
// [32][520], P bf16 [64][520]. One barrier; P is wave-local.
__global__ __launch_bounds__(256, 1)
void attn_mfma(const short* __restrict__ qkv, __hip_bfloat16* __restrict__ ctx)
{
    const int qt = blockIdx.x & 7;
    const int h  = (blockIdx.x >> 3) & 7;
    const int b  = blockIdx.x >> 6;
    __shared__ short Ks[512][40];    // 40 KiB
    __shared__ short Vt[32][520];    // 32.5 KiB
    __shared__ short Ps[64][520];    // 65 KiB
    const int tid = threadIdx.x;
    const int lane = tid & 63, wq = tid >> 6;
    const short* base = qkv + (size_t)b * NN_ * 768;

    {   // stage K: [key][d], coalesced 16B/lane
        const int d0 = (tid & 3) << 3;
        const int k0 = tid >> 2;
        #pragma unroll
        for (int rep = 0; rep < 8; ++rep) {
            const int key = k0 + rep * 64;
            *(bx8*)&Ks[key][d0] =
                *(const bx8*)(base + (size_t)key * 768 + 256 + h * 32 + d0);
        }
    }
    {   // stage V transposed: Vt[d][key]
        const int d0 = (tid >> 6) << 3;
        const int k0 = tid & 63;
        #pragma unroll
        for (int rep = 0; rep < 8; ++rep) {
            const int key = k0 + rep * 64;
            bx8 vv = *(const bx8*)(base + (size_t)key * 768 + 512 + h * 32 + d0);
            #pragma unroll
            for (int j = 0; j < 8; ++j) Vt[d0 + j][key] = vv[j];
        }
    }
    // Q fragment: row = lane&15 (q within wave tile), k = d = (lane>>4)*8+j
    const int fr = lane & 15, fk = (lane >> 4) << 3;
    const int qrow = qt * 64 + wq * 16 + fr;
    bx8 qf = *(const bx8*)(base + (size_t)qrow * 768 + h * 32 + fk);
    __syncthreads();

    // S = Q @ K^T : 32 n-tiles, single k-step (K=32)
    fx4 sc[32];
    #pragma unroll
    for (int nt = 0; nt < 32; ++nt) {
        bx8 kf = *(const bx8*)&Ks[nt * 16 + fr][fk];
        fx4 z = {0.f, 0.f, 0.f, 0.f};
        sc[nt] = __builtin_amdgcn_mfma_f32_16x16x32_bf16(qf, kf, z, 0, 0, 0);
    }

    // softmax: row = (lane>>4)*4 + r held across 16 lanes (lane&15) x 32 regs
    const float scale = 0.17677669529663687f;   // 1/sqrt(32)
    #pragma unroll
    for (int r = 0; r < 4; ++r) {
        float m = -1e30f;
        #pragma unroll
        for (int nt = 0; nt < 32; ++nt) m = fmaxf(m, sc[nt][r]);
        #pragma unroll
        for (int off = 1; off < 16; off <<= 1)
            m = fmaxf(m, __shfl_xor(m, off, 64));
        const float M = m * scale;
        float s = 0.f;
        #pragma unroll
        for (int nt = 0; nt < 32; ++nt) {
            const float p = __expf(sc[nt][r] * scale - M);
            sc[nt][r] = p;
            s += p;
        }
        #pragma unroll
        for (int off = 1; off < 16; off <<= 1) s += __shfl_xor(s, off, 64);
        const float inv = 1.0f / s;
        const int q = wq * 16 + (lane >> 4) * 4 + r;
        #pragma unroll
        for (int nt = 0; nt < 32; ++nt)
            *(__hip_bfloat16*)&Ps[q][nt * 16 + fr] = __float2bfloat16(sc[nt][r] * inv);
    }

    // O = P @ V : A=Ps (row=q=lane&15), B=Vt (col=d=lane&15), K=512
    fx4 oacc[2] = {};
    #pragma unroll
    for (int step = 0; step < 16; ++step) {
        bx8 pf = *(const bx8*)&Ps[wq * 16 + fr][step * 32 + fk];
        #pragma unroll
        for (int nt = 0; nt < 2; ++nt) {
            bx8 vf = *(const bx8*)&Vt[nt * 16 + fr][step * 32 + fk];
            oacc[nt] = __builtin_amdgcn_mfma_f32_16x16x32_bf16(pf, vf, oacc[nt], 0, 0, 0);
        }
    }
    #pragma unroll
    for (int nt = 0; nt < 2; ++nt) {
        #pragma unroll
        for (int r = 0; r < 4; ++r) {
            const int q = qt * 64 + wq * 16 + (lane >> 4) * 4 + r;
            const int d = nt * 16 + fr;
            ctx[(size_t)(b * NN_ + q) * D_ + h * 32 + d] = __float2bfloat16(oacc[nt][r]);
        }
    }
}

extern "C" void kernel_launch(void* const* d_in, const int* in_sizes, int n_in,
                              void* d_out, int out_size, void* d_ws, size_t ws_size,
                              hipStream_t stream) {
    const float* x      = (const float*)d_in[0];
    const int*   erows  = (const int*)d_in[1];
    const int*   ecols  = (const int*)d_in[2];
    const float* evals  = (const float*)d_in[3];
    const float* w_gcn  = (const float*)d_in[4];
    const float* in_w   = (const float*)d_in[5];
    const float* in_b   = (const float*)d_in[6];
    const float* outw   = (const float*)d_in[7];
    const float* outb   = (const float*)d_in[8];
    const float* w1     = (const float*)d_in[9];
    const float* b1     = (const float*)d_in[10];
    const float* w2     = (const float*)d_in[11];
    const float* b2     = (const float*)d_in[12];
    const float* bn1g = (const float*)d_in[15], *bn1b = (const float*)d_in[16];
    const float* bn1m = (const float*)d_in[17], *bn1v = (const float*)d_in[18];
    const float* bn2g = (const float*)d_in[19], *bn2b = (const float*)d_in[20];
    const float* bn2m = (const float*)d_in[21], *bn2v = (const float*)d_in[22];
    const float* bn3g = (const float*)d_in[23], *bn3b = (const float*)d_in[24];
    const float* bn3m = (const float*)d_in[25], *bn3v = (const float*)d_in[26];

    short* wsS = (short*)d_ws;
    __hip_bfloat16* xb    = (__hip_bfloat16*)(wsS + 0);
    __hip_bfloat16* wgcnb = (__hip_bfloat16*)(wsS + 2097152);
    __hip_bfloat16* iwb   = (__hip_bfloat16*)(wsS + 2162688);
    __hip_bfloat16* owb   = (__hip_bfloat16*)(wsS + 2359296);
    __hip_bfloat16* w1b   = (__hip_bfloat16*)(wsS + 2424832);
    __hip_bfloat16* w2b   = (__hip_bfloat16*)(wsS + 2686976);
    short* hl   = wsS + 2949120;      // 8192x256 bf16
    short* hlB  = wsS + 5046272;      // 16 x 256 x 512 bf16
    short* x1b  = wsS + 7143424;      // 8192x256
    short* ctxb = wsS + 9240576;      // 8192x256
    short* x2b  = wsS + 11337728;     // 8192x256
    short* h1b  = wsS + 13434880;     // 8192x1024
    short* SAb  = wsS + 21823488;     // 16x512x512 bf16
    float* SA   = (float*)(wsS + 26017792);   // 16x512x512 f32 (dead after conv)
    short* qkvb = wsS + 26017792;             // 8192x768 bf16 (overlaps SA)
    float* out  = (float*)d_out;

    dim3 blk(256);
    // converts of static inputs
    conv6<<<dim3(2880), blk, 0, stream>>>(x, w_gcn, in_w, outw, w1, w2,
                                          xb, wgcnb, iwb, owb, w1b, w2b);
    // dense adjacency
    hipMemsetAsync(SA, 0, (size_t)16 * 512 * 512 * 4, stream);
    build_S<<<dim3(1024), blk, 0, stream>>>(erows, ecols, evals, SA);
    convA<<<dim3(4096), blk, 0, stream>>>(SA, (__hip_bfloat16*)SAb, 1048576);
    // 1. hl = xb @ wgcnb^T   (bf16 out)
    mgemm<0,1,0><<<dim3(2, 64, 1), blk, 0, stream>>>((const short*)xb, (const short*)wgcnb,
        nullptr, hl, NT_, D_, D_, 0,0,0,0, nullptr, nullptr, nullptr, nullptr, nullptr);
    // 2. transpose
    transp<<<dim3(4, 8, 16), blk, 0, stream>>>((const __hip_bfloat16*)hl, (__hip_bfloat16*)hlB);
    // 3. x1 = bn1(x + gelu(S @ hl))  batched per graph
    mgemm<3,1,0><<<dim3(2, 4, 16), blk, 0, stream>>>(SAb, hlB, nullptr, x1b,
        512, D_, 512, 262144, 131072, 131072, 131072,
        x, bn1g, bn1b, bn1m, bn1v);
    // 4. qkv = x1b @ iwb^T + in_b   (bf16 out)
    mgemm<0,1,0><<<dim3(6, 64, 1), blk, 0, stream>>>(x1b, (const short*)iwb, in_b, qkvb,
        NT_, 3 * D_, D_, 0,0,0,0, nullptr, nullptr, nullptr, nullptr, nullptr);
    // 5. attention -> ctx (bf16), MFMA
    attn_mfma<<<dim3(1024), blk, 0, stream>>>(qkvb, (__hip_bfloat16*)ctxb);
    // 6. x2 = bn2(x1 + ctx @ owb^T + outb)
    mgemm<2,1,1><<<dim3(2, 64, 1), blk, 0, stream>>>(ctxb, (const short*)owb, outb, x2b,
        NT_, D_, D_, 0,0,0,0, x1b, bn2g, bn2b, bn2m, bn2v);
    // 7. h1 = gelu(x2 @ w1b^T + b1)
    mgemm<1,1,0><<<dim3(8, 64, 1), blk, 0, stream>>>(x2b, (const short*)w1b, b1, h1b,
        NT_, 4 * D_, D_, 0,0,0,0, nullptr, nullptr, nullptr, nullptr, nullptr);
    // 8. out = bn3(x2 + h1 @ w2b^T + b2)   (f32 out)
    mgemm<2,0,1><<<dim3(2, 64, 1), blk, 0, stream>>>(h1b, (const short*)w2b, b2, out,
        NT_, D_, 4 * D_, 0,0,0,0, x2b, bn3g, bn3b, bn3m, bn3v);
}

// Round 6
// 258.021 us; speedup vs baseline: 4.7929x; 1.2683x over previous
//
#include <hip/hip_runtime.h>
#include <hip/hip_bf16.h>
#include <math.h>

#define D_    256
#define NT_   8192
#define NN_   512
#define B_    16
#define H_    8
#define EPG_  16384
#define BN_EPS 1e-5f

typedef __attribute__((ext_vector_type(8))) short bx8;
typedef __attribute__((ext_vector_type(4))) float fx4;

__device__ __forceinline__ float gelu_exact(float x) {
    return 0.5f * x * (1.0f + erff(x * 0.70710678118654752f));
}

// async global->LDS 16B per lane; lds dest wave-uniform base, gsrc per-lane
typedef __attribute__((address_space(1))) const unsigned int GU;
typedef __attribute__((address_space(3))) unsigned int LU;
__device__ __forceinline__ void gl_lds16(const void* g, void* l) {
    __builtin_amdgcn_global_load_lds((GU*)g, (LU*)l, 16, 0, 0);
}

// ============ bf16 MFMA GEMM: C = A(MxK) @ B(NxK)^T (+bias)(+epi) =========
// Tile TM x TN (TM,TN in {64,128}), BK=32, 4 waves as 2x2 wave-grid.
// EPI: 0 none, 1 gelu, 2 resid+BN, 3 resid+gelu(acc)+BN
// OBF: output bf16 (else f32). RBF: resid bf16 (else f32).
template<int TM, int TN, int EPI, int OBF, int RBF>
__global__ __launch_bounds__(256)
void mgemm(const short* __restrict__ A, const short* __restrict__ Bw,
           const float* __restrict__ bias, void* __restrict__ Cout,
           int M, int N, int K,
           long sA, long sB, long sC, long sR,
           const void* __restrict__ resid,
           const float* __restrict__ bng, const float* __restrict__ bnb,
           const float* __restrict__ bnm, const float* __restrict__ bnv)
{
    constexpr int MR = TM / 32, NR = TN / 32;   // per-wave 16x16 frags
    constexpr int IA = TM / 16, IB = TN / 16;   // 1KiB staging issues
    __shared__ short As[TM][32];
    __shared__ short Bs[TN][32];
    const int bz = blockIdx.z;
    A  += (size_t)bz * sA;
    Bw += (size_t)bz * sB;
    const int bm = blockIdx.y * TM, bn = blockIdx.x * TN;
    const int tid = threadIdx.x;
    const int w = tid >> 6, lane = tid & 63;
    const int wm = w >> 1, wn = w & 1;
    const int fr = lane & 15, fk = (lane >> 4) << 3;
    const int srow = lane >> 2, scol = (lane & 3) << 3;  // within-issue map
    fx4 acc[MR][NR] = {};

    for (int k0 = 0; k0 < K; k0 += 32) {
        __syncthreads();   // prior compute done before LDS overwrite
        #pragma unroll
        for (int i = w; i < IA + IB; i += 4) {
            if (i < IA)
                gl_lds16(A + (size_t)(bm + i * 16 + srow) * K + k0 + scol,
                         (char*)As + i * 1024);
            else
                gl_lds16(Bw + (size_t)(bn + (i - IA) * 16 + srow) * K + k0 + scol,
                         (char*)Bs + (i - IA) * 1024);
        }
        __syncthreads();   // vmcnt drained by compiler before barrier
        bx8 af[MR], bf[NR];
        #pragma unroll
        for (int m = 0; m < MR; ++m) af[m] = *(const bx8*)&As[wm * (TM / 2) + m * 16 + fr][fk];
        #pragma unroll
        for (int n = 0; n < NR; ++n) bf[n] = *(const bx8*)&Bs[wn * (TN / 2) + n * 16 + fr][fk];
        #pragma unroll
        for (int m = 0; m < MR; ++m)
            #pragma unroll
            for (int n = 0; n < NR; ++n)
                acc[m][n] = __builtin_amdgcn_mfma_f32_16x16x32_bf16(af[m], bf[n], acc[m][n], 0, 0, 0);
    }

    float* Cf = (float*)Cout + (size_t)bz * sC;
    __hip_bfloat16* Cb = (__hip_bfloat16*)Cout + (size_t)bz * sC;
    const float* Rf = (const float*)resid + (EPI >= 2 ? (size_t)bz * sR : 0);
    const __hip_bfloat16* Rb = (const __hip_bfloat16*)resid + (EPI >= 2 ? (size_t)bz * sR : 0);
    #pragma unroll
    for (int m = 0; m < MR; ++m) {
        #pragma unroll
        for (int n = 0; n < NR; ++n) {
            #pragma unroll
            for (int r = 0; r < 4; ++r) {
                const int gm = bm + wm * (TM / 2) + m * 16 + (lane >> 4) * 4 + r;
                const int gn = bn + wn * (TN / 2) + n * 16 + fr;
                float v = acc[m][n][r];
                if (bias) v += bias[gn];
                if (EPI == 1) v = gelu_exact(v);
                if (EPI == 2 || EPI == 3) {
                    const float rv = RBF ? __bfloat162float(Rb[(size_t)gm * N + gn])
                                         : Rf[(size_t)gm * N + gn];
                    if (EPI == 2) v += rv;
                    else          v = rv + gelu_exact(v);
                    v = (v - bnm[gn]) * (bng[gn] * rsqrtf(bnv[gn] + BN_EPS)) + bnb[gn];
                }
                if (OBF) Cb[(size_t)gm * N + gn] = __float2bfloat16(v);
                else     Cf[(size_t)gm * N + gn] = v;
            }
        }
    }
}

// ============ converts ======================================================
__device__ __forceinline__ void cv4(const float4 v, __hip_bfloat16* d) {
    __hip_bfloat162* dp = (__hip_bfloat162*)d;
    dp[0] = __hip_bfloat162(__float2bfloat16(v.x), __float2bfloat16(v.y));
    dp[1] = __hip_bfloat162(__float2bfloat16(v.z), __float2bfloat16(v.w));
}

__global__ __launch_bounds__(256)
void conv6(const float* __restrict__ x,  const float* __restrict__ wg,
           const float* __restrict__ iw, const float* __restrict__ ow,
           const float* __restrict__ w1, const float* __restrict__ w2,
           __hip_bfloat16* xb, __hip_bfloat16* wgb, __hip_bfloat16* iwb,
           __hip_bfloat16* owb, __hip_bfloat16* w1b, __hip_bfloat16* w2b)
{
    int i = blockIdx.x * 256 + threadIdx.x;   // float4 index
    const float* s; __hip_bfloat16* d; int o;
    if      (i < 524288) { s = x;  d = xb;  o = i; }
    else if (i < 540672) { s = wg; d = wgb; o = i - 524288; }
    else if (i < 589824) { s = iw; d = iwb; o = i - 540672; }
    else if (i < 606208) { s = ow; d = owb; o = i - 589824; }
    else if (i < 671744) { s = w1; d = w1b; o = i - 606208; }
    else                 { s = w2; d = w2b; o = i - 671744; }
    cv4(((const float4*)s)[o], d + (size_t)o * 4);
}

__global__ __launch_bounds__(256)
void convA(const float* __restrict__ s, __hip_bfloat16* __restrict__ d, int n4)
{
    int i = blockIdx.x * 256 + threadIdx.x;
    if (i >= n4) return;
    cv4(((const float4*)s)[i], d + (size_t)i * 4);
}

// ============ dense adjacency build ========================================
__global__ __launch_bounds__(256)
void build_S(const int* __restrict__ rows, const int* __restrict__ cols,
             const float* __restrict__ vals, float* __restrict__ SA)
{
    const int e = blockIdx.x * 256 + threadIdx.x;   // 262144 edges
    const int r = rows[e], c = cols[e];
    const int g = r >> 9;
    atomicAdd(&SA[((size_t)g << 18) + (size_t)(r & 511) * 512 + (c - (g << 9))], vals[e]);
}

// ============ transpose hl (8192x256) -> hlB[g][256][512] ==================
__global__ __launch_bounds__(256)
void transp(const __hip_bfloat16* __restrict__ hl, __hip_bfloat16* __restrict__ hlB)
{
    __shared__ short T[64][72];
    const int nt = blockIdx.x, it = blockIdx.y, g = blockIdx.z;
    const int r0 = threadIdx.x >> 3, c8 = (threadIdx.x & 7) << 3;  // r0 in [0,32)
    #pragma unroll
    for (int u = 0; u < 2; ++u) {
        const int r = r0 + u * 32;
        *(bx8*)&T[r][c8] = *(const bx8*)&hl[(size_t)(g * 512 + it * 64 + r) * 256 + nt * 64 + c8];
    }
    __syncthreads();
    #pragma unroll
    for (int u = 0; u < 2; ++u) {
        const int r = r0 + u * 32;
        bx8 o;
        #pragma unroll
        for (int j = 0; j < 8; ++j) o[j] = T[c8 + j][r];
        *(bx8*)&hlB[((size_t)(g * 256 + nt * 64 + r)) * 512 + it * 64 + c8] = o;
    }
}

// ============ MFMA flash attention: block = (b, h, 64 q-rows) ==============
__global__ __launch_bounds__(256, 1)
void attn_mfma(const short* __restrict__ qkv, __hip_bfloat16* __restrict__ ctx)
{
    const int qt = blockIdx.x & 7;
    const int h  = (blockIdx.x >> 3) & 7;
    const int b  = blockIdx.x >> 6;
    __shared__ short Ks[512][40];
    __shared__ short Vt[32][520];
    __shared__ short Ps[64][520];
    const int tid = threadIdx.x;
    const int lane = tid & 63, wq = tid >> 6;
    const short* base = qkv + (size_t)b * NN_ * 768;

    {
        const int d0 = (tid & 3) << 3;
        const int k0 = tid >> 2;
        #pragma unroll
        for (int rep = 0; rep < 8; ++rep) {
            const int key = k0 + rep * 64;
            *(bx8*)&Ks[key][d0] =
                *(const bx8*)(base + (size_t)key * 768 + 256 + h * 32 + d0);
        }
    }
    {
        const int d0 = (tid >> 6) << 3;
        const int k0 = tid & 63;
        #pragma unroll
        for (int rep = 0; rep < 8; ++rep) {
            const int key = k0 + rep * 64;
            bx8 vv = *(const bx8*)(base + (size_t)key * 768 + 512 + h * 32 + d0);
            #pragma unroll
            for (int j = 0; j < 8; ++j) Vt[d0 + j][key] = vv[j];
        }
    }
    const int fr = lane & 15, fk = (lane >> 4) << 3;
    const int qrow = qt * 64 + wq * 16 + fr;
    bx8 qf = *(const bx8*)(base + (size_t)qrow * 768 + h * 32 + fk);
    __syncthreads();

    fx4 sc[32];
    #pragma unroll
    for (int nt = 0; nt < 32; ++nt) {
        bx8 kf = *(const bx8*)&Ks[nt * 16 + fr][fk];
        fx4 z = {0.f, 0.f, 0.f, 0.f};
        sc[nt] = __builtin_amdgcn_mfma_f32_16x16x32_bf16(qf, kf, z, 0, 0, 0);
    }

    const float scale = 0.17677669529663687f;   // 1/sqrt(32)
    #pragma unroll
    for (int r = 0; r < 4; ++r) {
        float m = -1e30f;
        #pragma unroll
        for (int nt = 0; nt < 32; ++nt) m = fmaxf(m, sc[nt][r]);
        #pragma unroll
        for (int off = 1; off < 16; off <<= 1)
            m = fmaxf(m, __shfl_xor(m, off, 64));
        const float M = m * scale;
        float s = 0.f;
        #pragma unroll
        for (int nt = 0; nt < 32; ++nt) {
            const float p = __expf(sc[nt][r] * scale - M);
            sc[nt][r] = p;
            s += p;
        }
        #pragma unroll
        for (int off = 1; off < 16; off <<= 1) s += __shfl_xor(s, off, 64);
        const float inv = 1.0f / s;
        const int q = wq * 16 + (lane >> 4) * 4 + r;
        #pragma unroll
        for (int nt = 0; nt < 32; ++nt)
            *(__hip_bfloat16*)&Ps[q][nt * 16 + fr] = __float2bfloat16(sc[nt][r] * inv);
    }

    fx4 oacc[2] = {};
    #pragma unroll
    for (int step = 0; step < 16; ++step) {
        bx8 pf = *(const bx8*)&Ps[wq * 16 + fr][step * 32 + fk];
        #pragma unroll
        for (int nt = 0; nt < 2; ++nt) {
            bx8 vf = *(const bx8*)&Vt[nt * 16 + fr][step * 32 + fk];
            oacc[nt] = __builtin_amdgcn_mfma_f32_16x16x32_bf16(pf, vf, oacc[nt], 0, 0, 0);
        }
    }
    #pragma unroll
    for (int nt = 0; nt < 2; ++nt) {
        #pragma unroll
        for (int r = 0; r < 4; ++r) {
            const int q = qt * 64 + wq * 16 + (lane >> 4) * 4 + r;
            const int d = nt * 16 + fr;
            ctx[(size_t)(b * NN_ + q) * D_ + h * 32 + d] = __float2bfloat16(oacc[nt][r]);
        }
    }
}

extern "C" void kernel_launch(void* const* d_in, const int* in_sizes, int n_in,
                              void* d_out, int out_size, void* d_ws, size_t ws_size,
                              hipStream_t stream) {
    const float* x      = (const float*)d_in[0];
    const int*   erows  = (const int*)d_in[1];
    const int*   ecols  = (const int*)d_in[2];
    const float* evals  = (const float*)d_in[3];
    const float* w_gcn  = (const float*)d_in[4];
    const float* in_w   = (const float*)d_in[5];
    const float* in_b   = (const float*)d_in[6];
    const float* outw   = (const float*)d_in[7];
    const float* outb   = (const float*)d_in[8];
    const float* w1     = (const float*)d_in[9];
    const float* b1     = (const float*)d_in[10];
    const float* w2     = (const float*)d_in[11];
    const float* b2     = (const float*)d_in[12];
    const float* bn1g = (const float*)d_in[15], *bn1b = (const float*)d_in[16];
    const float* bn1m = (const float*)d_in[17], *bn1v = (const float*)d_in[18];
    const float* bn2g = (const float*)d_in[19], *bn2b = (const float*)d_in[20];
    const float* bn2m = (const float*)d_in[21], *bn2v = (const float*)d_in[22];
    const float* bn3g = (const float*)d_in[23], *bn3b = (const float*)d_in[24];
    const float* bn3m = (const float*)d_in[25], *bn3v = (const float*)d_in[26];

    short* wsS = (short*)d_ws;
    __hip_bfloat16* xb    = (__hip_bfloat16*)(wsS + 0);
    __hip_bfloat16* wgcnb = (__hip_bfloat16*)(wsS + 2097152);
    __hip_bfloat16* iwb   = (__hip_bfloat16*)(wsS + 2162688);
    __hip_bfloat16* owb   = (__hip_bfloat16*)(wsS + 2359296);
    __hip_bfloat16* w1b   = (__hip_bfloat16*)(wsS + 2424832);
    __hip_bfloat16* w2b   = (__hip_bfloat16*)(wsS + 2686976);
    short* hl   = wsS + 2949120;      // 8192x256 bf16
    short* hlB  = wsS + 5046272;      // 16 x 256 x 512 bf16
    short* x1b  = wsS + 7143424;      // 8192x256
    short* ctxb = wsS + 9240576;      // 8192x256
    short* x2b  = wsS + 11337728;     // 8192x256
    short* h1b  = wsS + 13434880;     // 8192x1024
    short* SAb  = wsS + 21823488;     // 16x512x512 bf16
    float* SA   = (float*)(wsS + 26017792);   // 16x512x512 f32 (dead after conv)
    short* qkvb = wsS + 26017792;             // 8192x768 bf16 (overlaps SA)
    float* out  = (float*)d_out;

    dim3 blk(256);
    // converts of static inputs
    conv6<<<dim3(2880), blk, 0, stream>>>(x, w_gcn, in_w, outw, w1, w2,
                                          xb, wgcnb, iwb, owb, w1b, w2b);
    // dense adjacency
    hipMemsetAsync(SA, 0, (size_t)16 * 512 * 512 * 4, stream);
    build_S<<<dim3(1024), blk, 0, stream>>>(erows, ecols, evals, SA);
    convA<<<dim3(4096), blk, 0, stream>>>(SA, (__hip_bfloat16*)SAb, 1048576);
    // 1. hl = xb @ wgcnb^T   (bf16 out)
    mgemm<64,64,0,1,0><<<dim3(4, 128), blk, 0, stream>>>((const short*)xb, (const short*)wgcnb,
        nullptr, hl, NT_, D_, D_, 0,0,0,0, nullptr, nullptr, nullptr, nullptr, nullptr);
    // 2. transpose
    transp<<<dim3(4, 8, 16), blk, 0, stream>>>((const __hip_bfloat16*)hl, (__hip_bfloat16*)hlB);
    // 3. x1 = bn1(x + gelu(S @ hl))  batched per graph
    mgemm<64,64,3,1,0><<<dim3(4, 8, 16), blk, 0, stream>>>(SAb, hlB, nullptr, x1b,
        512, D_, 512, 262144, 131072, 131072, 131072,
        x, bn1g, bn1b, bn1m, bn1v);
    // 4. qkv = x1b @ iwb^T + in_b   (bf16 out)
    mgemm<128,64,0,1,0><<<dim3(12, 64), blk, 0, stream>>>(x1b, (const short*)iwb, in_b, qkvb,
        NT_, 3 * D_, D_, 0,0,0,0, nullptr, nullptr, nullptr, nullptr, nullptr);
    // 5. attention -> ctx (bf16), MFMA
    attn_mfma<<<dim3(1024), blk, 0, stream>>>(qkvb, (__hip_bfloat16*)ctxb);
    // 6. x2 = bn2(x1 + ctx @ owb^T + outb)
    mgemm<64,64,2,1,1><<<dim3(4, 128), blk, 0, stream>>>(ctxb, (const short*)owb, outb, x2b,
        NT_, D_, D_, 0,0,0,0, x1b, bn2g, bn2b, bn2m, bn2v);
    // 7. h1 = gelu(x2 @ w1b^T + b1)
    mgemm<128,64,1,1,0><<<dim3(16, 64), blk, 0, stream>>>(x2b, (const short*)w1b, b1, h1b,
        NT_, 4 * D_, D_, 0,0,0,0, nullptr, nullptr, nullptr, nullptr, nullptr);
    // 8. out = bn3(x2 + h1 @ w2b^T + b2)   (f32 out)
    mgemm<64,64,2,0,1><<<dim3(4, 128), blk, 0, stream>>>(h1b, (const short*)w2b, b2, out,
        NT_, D_, 4 * D_, 0,0,0,0, x2b, bn3g, bn3b, bn3m, bn3v);
}